// Round 9
// baseline (632.376 us; speedup 1.0000x reference)
//
#include <hip/hip_runtime.h>
#include <cstdint>
#include <cstddef>

// GraphCluster: 3-layer GCN + assign head, 100K nodes / 1.6M edges.
// R1: hierarchical scan. R2: f16-MFMA GEMMs. R3: f16 intermediates.
// R4 bucketed fill REVERTED (hot-cursor atomics). R6 agg unroll-8 REVERTED.
// R7: scan-based counting-sort CSR build (zero contended atomics).
// R8: LDS-free GEMM — A-frags loaded direct from global (16B/lane), W
// pre-transposed to f16 once (wprep_k); kills 1.3e7 bank conflicts + LDS
// occupancy cap. agg128h near gather roofline (410MB logical @ 6.2TB/s).

#define SCAN_CHUNK 2048

typedef _Float16 half8 __attribute__((ext_vector_type(8)));
typedef float floatx4 __attribute__((ext_vector_type(4)));

// ---------------------------------------------------------------- generic scan
__global__ __launch_bounds__(256) void scan_partial_k(const int* __restrict__ cnt, int N,
                                                      int* __restrict__ bsum) {
  __shared__ int red[256];
  int b = blockIdx.x, t = threadIdx.x;
  int base = b * SCAN_CHUNK + t * 8;
  int s = 0;
#pragma unroll
  for (int i = 0; i < 8; ++i) {
    int idx = base + i;
    if (idx < N) s += cnt[idx];
  }
  red[t] = s;
  __syncthreads();
  for (int off = 128; off > 0; off >>= 1) {
    if (t < off) red[t] += red[t + off];
    __syncthreads();
  }
  if (t == 0) bsum[b] = red[0];
}

__global__ __launch_bounds__(64) void scan_bsum_k(int* __restrict__ bsum, int NB) {
  int lane = threadIdx.x;
  int per = (NB + 63) >> 6;
  int beg = lane * per;
  int end = min(beg + per, NB);
  int s = 0;
  for (int i = beg; i < end; ++i) s += bsum[i];
  int ps = s;
  for (int off = 1; off < 64; off <<= 1) {
    int u = __shfl_up(ps, off, 64);
    if (lane >= off) ps += u;
  }
  int run = ps - s;
  for (int i = beg; i < end; ++i) {
    int c = bsum[i];
    bsum[i] = run;
    run += c;
  }
}

__global__ __launch_bounds__(256) void scan_apply_k(const int* __restrict__ cnt,
                                                    const int* __restrict__ bsum_excl, int N,
                                                    int* __restrict__ rowptr,
                                                    int* __restrict__ cursor, int E) {
  __shared__ int wave_sums[4];
  int b = blockIdx.x, t = threadIdx.x;
  int base = b * SCAN_CHUNK + t * 8;
  int v[8];
  int s = 0;
#pragma unroll
  for (int i = 0; i < 8; ++i) {
    int idx = base + i;
    v[i] = (idx < N) ? cnt[idx] : 0;
    s += v[i];
  }
  int lane = t & 63, wave = t >> 6;
  int ps = s;
  for (int off = 1; off < 64; off <<= 1) {
    int u = __shfl_up(ps, off, 64);
    if (lane >= off) ps += u;
  }
  if (lane == 63) wave_sums[wave] = ps;
  __syncthreads();
  int woff = 0;
  for (int w = 0; w < 4; ++w)
    if (w < wave) woff += wave_sums[w];
  int excl = woff + (ps - s) + bsum_excl[b];
#pragma unroll
  for (int i = 0; i < 8; ++i) {
    int idx = base + i;
    if (idx < N) {
      rowptr[idx] = excl;
      cursor[idx] = excl;
      excl += v[i];
    }
  }
  if (b == 0 && t == 0) rowptr[N] = E;
}

// ------------------------------------------------- scan-sorted CSR build
__global__ __launch_bounds__(256) void p1a_hist_k(const int* __restrict__ dst, int E, int G,
                                                  int B, int chunk, int* __restrict__ M) {
  __shared__ int h[256];
  int g = blockIdx.x, t = threadIdx.x;
  for (int i = t; i < B; i += 256) h[i] = 0;
  __syncthreads();
  int ebeg = g * chunk, eend = min(ebeg + chunk, E);
  for (int e = ebeg + t; e < eend; e += 256) atomicAdd(&h[dst[e] >> 9], 1);
  __syncthreads();
  for (int b = t; b < B; b += 256) M[(size_t)b * G + g] = h[b];
}

__global__ __launch_bounds__(256) void p1c_scatter_k(const int* __restrict__ src,
                                                     const int* __restrict__ dst, int E, int G,
                                                     int B, int chunk,
                                                     const int* __restrict__ scanned,
                                                     uint32_t* __restrict__ tmp) {
  __shared__ int off[256];
  int g = blockIdx.x, t = threadIdx.x;
  for (int b = t; b < B; b += 256) off[b] = scanned[(size_t)b * G + g];
  __syncthreads();
  int ebeg = g * chunk, eend = min(ebeg + chunk, E);
  for (int e = ebeg + t; e < eend; e += 256) {
    int d = dst[e];
    int b = d >> 9;
    int pos = atomicAdd(&off[b], 1);  // LDS cursor, private to this block
    tmp[pos] = ((uint32_t)(d & 511) << 17) | (uint32_t)src[e];
  }
}

__global__ __launch_bounds__(256) void p2_build_k(const uint32_t* __restrict__ tmp,
                                                  const int* __restrict__ scanned, int G, int N,
                                                  int E, int* __restrict__ rowptr,
                                                  int* __restrict__ col,
                                                  float* __restrict__ dinv) {
  __shared__ int hist[512];
  __shared__ int cur[512];
  __shared__ int wsum[4];
  int b = blockIdx.x, t = threadIdx.x;
  int node0 = b << 9;
  int nn = min(512, N - node0);
  int sbeg = scanned[(size_t)b * G];
  int send = scanned[(size_t)(b + 1) * G];
  for (int i = t; i < 512; i += 256) hist[i] = 0;
  __syncthreads();
  for (int e = sbeg + t; e < send; e += 256) atomicAdd(&hist[tmp[e] >> 17], 1);
  __syncthreads();
  int h0 = hist[2 * t], h1 = hist[2 * t + 1];
  int s = h0 + h1;
  int lane = t & 63, w = t >> 6;
  int ps = s;
  for (int o = 1; o < 64; o <<= 1) {
    int u = __shfl_up(ps, o, 64);
    if (lane >= o) ps += u;
  }
  if (lane == 63) wsum[w] = ps;
  __syncthreads();
  int woff = 0;
  for (int k = 0; k < 4; ++k)
    if (k < w) woff += wsum[k];
  int excl = sbeg + woff + (ps - s);
  if (2 * t < nn) {
    rowptr[node0 + 2 * t] = excl;
    cur[2 * t] = excl;
    dinv[node0 + 2 * t] = rsqrtf((float)(h0 + 1));
  }
  if (2 * t + 1 < nn) {
    rowptr[node0 + 2 * t + 1] = excl + h0;
    cur[2 * t + 1] = excl + h0;
    dinv[node0 + 2 * t + 1] = rsqrtf((float)(h1 + 1));
  }
  if (b == 0 && t == 0) rowptr[N] = E;
  __syncthreads();
  for (int e = sbeg + t; e < send; e += 256) {
    uint32_t u = tmp[e];
    int pos = atomicAdd(&cur[u >> 17], 1);
    col[pos] = (int)(u & 0x1FFFF);
  }
}

// ------------------------------------------------- fallback CSR build (N large)
__global__ __launch_bounds__(256) void count_edges_k(const int* __restrict__ dst, int E,
                                                     int* __restrict__ cnt) {
  int idx = blockIdx.x * blockDim.x + threadIdx.x;
  int stride = gridDim.x * blockDim.x;
  for (int e = idx; e < E; e += stride) atomicAdd(&cnt[dst[e]], 1);
}

__global__ __launch_bounds__(256) void dinv_k(const int* __restrict__ cnt,
                                              float* __restrict__ dinv, int N) {
  int i = blockIdx.x * blockDim.x + threadIdx.x;
  if (i < N) dinv[i] = rsqrtf((float)(cnt[i] + 1));
}

__global__ __launch_bounds__(256) void fill_k(const int* __restrict__ src,
                                              const int* __restrict__ dst, int E,
                                              int* __restrict__ cursor, int* __restrict__ col) {
  int idx = blockIdx.x * blockDim.x + threadIdx.x;
  int stride = gridDim.x * blockDim.x;
  for (int e = idx; e < E; e += stride) {
    int d = dst[e];
    int pos = atomicAdd(&cursor[d], 1);
    col[pos] = src[e];
  }
}

// ---------------------------------------------------------------- weight prep
// Wt layout (f16, transposed): mat 0..4 are 128x128 at offset mat*16384,
// assign (16x128) at 5*16384. Wt[n*128+k] = W[k*NCOL+n].
__global__ __launch_bounds__(256) void wprep_k(const float* __restrict__ fc1_W,
                                               const float* __restrict__ fc2_W,
                                               const float* __restrict__ gcn_W,
                                               const float* __restrict__ assign_W,
                                               _Float16* __restrict__ Wt) {
  int idx = blockIdx.x * 256 + threadIdx.x;
  if (idx < 5 * 16384) {
    int mat = idx >> 14;
    int r = idx & 16383;
    int n = r >> 7, k = r & 127;
    const float* W = (mat == 0) ? fc1_W : (mat == 1) ? fc2_W : gcn_W + (size_t)(mat - 2) * 16384;
    Wt[(size_t)mat * 16384 + (size_t)n * 128 + k] = (_Float16)W[(size_t)k * 128 + n];
  } else if (idx < 5 * 16384 + 2048) {
    int r = idx - 5 * 16384;
    int n = r >> 7, k = r & 127;
    Wt[5 * 16384 + (size_t)n * 128 + k] = (_Float16)assign_W[(size_t)k * 16 + n];
  }
}

// ---------------------------------------------------------------- LDS-free GEMM
// out[N,NCOL] = A[N,128] @ W[128,NCOL] via f16 MFMA; A-frags direct from
// global (A[m=lane&15][k=q*8+j] = 16 contiguous bytes of a row), B-frags from
// pre-transposed Wt (L1/L2-resident 32KB). No LDS, no barriers.
template <bool SIG, bool HIN, bool HOUT, int NT>
__global__ __launch_bounds__(256) void gemm_nolds_k(const void* __restrict__ Av,
                                                    const _Float16* __restrict__ Wt,
                                                    const float* __restrict__ bias,
                                                    const float* __restrict__ scale,
                                                    void* __restrict__ outv, int N) {
  constexpr int NCOL = NT * 16;
  const int tid = threadIdx.x;
  const int w = tid >> 6, lane = tid & 63;
  const int m = lane & 15, q = lane >> 4;
  const int rowA = blockIdx.x * 64 + w * 16 + m;  // A-operand row
  const bool validA = rowA < N;
  floatx4 acc[NT];
#pragma unroll
  for (int t = 0; t < NT; ++t) acc[t] = (floatx4){0.f, 0.f, 0.f, 0.f};
#pragma unroll
  for (int kt = 0; kt < 128; kt += 32) {
    half8 a = {0, 0, 0, 0, 0, 0, 0, 0};
    if (validA) {
      if (HIN) {
        a = *(const half8*)((const _Float16*)Av + (size_t)rowA * 128 + kt + q * 8);
      } else {
        const float* Ap = (const float*)Av + (size_t)rowA * 128 + kt + q * 8;
        float4 f0 = *(const float4*)Ap;
        float4 f1 = *(const float4*)(Ap + 4);
        a[0] = (_Float16)f0.x; a[1] = (_Float16)f0.y;
        a[2] = (_Float16)f0.z; a[3] = (_Float16)f0.w;
        a[4] = (_Float16)f1.x; a[5] = (_Float16)f1.y;
        a[6] = (_Float16)f1.z; a[7] = (_Float16)f1.w;
      }
    }
#pragma unroll
    for (int t = 0; t < NT; ++t) {
      half8 b = *(const half8*)(Wt + (size_t)(t * 16 + m) * 128 + kt + q * 8);
      acc[t] = __builtin_amdgcn_mfma_f32_16x16x32_f16(a, b, acc[t], 0, 0, 0);
    }
  }
  // epilogue: C/D layout col=lane&15 (=m), row_in_tile=q*4+r
#pragma unroll
  for (int r = 0; r < 4; ++r) {
    int row = blockIdx.x * 64 + w * 16 + q * 4 + r;
    if (row >= N) continue;
    float sc = scale ? scale[row] : 1.f;
#pragma unroll
    for (int t = 0; t < NT; ++t) {
      int colg = t * 16 + m;
      float v = acc[t][r];
      if (bias) v += bias[colg];
      if (SIG) v = 1.f / (1.f + __expf(-v));
      v *= sc;
      if (HOUT)
        ((_Float16*)outv)[(size_t)row * NCOL + colg] = (_Float16)v;
      else
        ((float*)outv)[(size_t)row * NCOL + colg] = v;
    }
  }
}

// ---------------------------------------------------------------- aggregation
// xw (f16, pre-scaled by dinv[row]): out[i] = b + dinv[i]*(xw[i]+sum xw[src]).
__global__ __launch_bounds__(256) void agg128h_k(const _Float16* __restrict__ xw,
                                                 const int* __restrict__ rowptr,
                                                 const int* __restrict__ col,
                                                 const float* __restrict__ dinv,
                                                 const float* __restrict__ bias,
                                                 _Float16* __restrict__ out, int N) {
  int node = blockIdx.x * 4 + (threadIdx.x >> 6);
  if (node >= N) return;
  int lane = threadIdx.x & 63;
  int fl = lane & 15;
  int j = lane >> 4;
  int beg = rowptr[node];
  int end = rowptr[node + 1];
  const _Float16* base = xw + (size_t)fl * 8;
  float a[8] = {0.f, 0.f, 0.f, 0.f, 0.f, 0.f, 0.f, 0.f};
  int e = beg + j;
  for (; e + 12 < end; e += 16) {
    int s0 = col[e], s1 = col[e + 4], s2 = col[e + 8], s3 = col[e + 12];
    half8 v0 = *(const half8*)(base + (size_t)s0 * 128);
    half8 v1 = *(const half8*)(base + (size_t)s1 * 128);
    half8 v2 = *(const half8*)(base + (size_t)s2 * 128);
    half8 v3 = *(const half8*)(base + (size_t)s3 * 128);
#pragma unroll
    for (int f = 0; f < 8; ++f)
      a[f] += ((float)v0[f] + (float)v1[f]) + ((float)v2[f] + (float)v3[f]);
  }
  for (; e < end; e += 4) {
    half8 v = *(const half8*)(base + (size_t)col[e] * 128);
#pragma unroll
    for (int f = 0; f < 8; ++f) a[f] += (float)v[f];
  }
  if (j == 0) {
    half8 v = *(const half8*)(base + (size_t)node * 128);
#pragma unroll
    for (int f = 0; f < 8; ++f) a[f] += (float)v[f];
  }
#pragma unroll
  for (int f = 0; f < 8; ++f) {
    a[f] += __shfl_xor(a[f], 16, 64);
    a[f] += __shfl_xor(a[f], 32, 64);
  }
  if (j == 0) {
    float di = dinv[node];
    float4 b0 = *(const float4*)(bias + fl * 8);
    float4 b1 = *(const float4*)(bias + fl * 8 + 4);
    half8 o;
    o[0] = (_Float16)fmaf(a[0], di, b0.x);
    o[1] = (_Float16)fmaf(a[1], di, b0.y);
    o[2] = (_Float16)fmaf(a[2], di, b0.z);
    o[3] = (_Float16)fmaf(a[3], di, b0.w);
    o[4] = (_Float16)fmaf(a[4], di, b1.x);
    o[5] = (_Float16)fmaf(a[5], di, b1.y);
    o[6] = (_Float16)fmaf(a[6], di, b1.z);
    o[7] = (_Float16)fmaf(a[7], di, b1.w);
    *(half8*)(out + (size_t)node * 128 + fl * 8) = o;
  }
}

__global__ __launch_bounds__(256) void agg16_k(const float* __restrict__ xw,
                                               const int* __restrict__ rowptr,
                                               const int* __restrict__ col,
                                               const float* __restrict__ dinv,
                                               const float* __restrict__ bias,
                                               float* __restrict__ out, int N) {
  int node = blockIdx.x * 4 + (threadIdx.x >> 6);
  if (node >= N) return;
  int lane = threadIdx.x & 63;
  int f = lane & 15;
  int j = lane >> 4;
  int beg = rowptr[node];
  int end = rowptr[node + 1];
  float acc = 0.f;
  for (int e = beg + j; e < end; e += 4) {
    acc += xw[(size_t)col[e] * 16 + f];
  }
  acc += __shfl_xor(acc, 16, 64);
  acc += __shfl_xor(acc, 32, 64);
  float o = fmaf(acc + xw[(size_t)node * 16 + f], dinv[node], bias[f]);
  if (j == 0) out[(size_t)node * 16 + f] = o;
}

// ---------------------------------------------------------------- launch
extern "C" void kernel_launch(void* const* d_in, const int* in_sizes, int n_in,
                              void* d_out, int out_size, void* d_ws, size_t ws_size,
                              hipStream_t stream) {
  const int* adj = (const int*)d_in[0];
  const float* X = (const float*)d_in[1];
  const float* fc1_W = (const float*)d_in[2];
  const float* fc1_b = (const float*)d_in[3];
  const float* fc2_W = (const float*)d_in[4];
  const float* fc2_b = (const float*)d_in[5];
  const float* gcn_W = (const float*)d_in[6];
  const float* gcn_b = (const float*)d_in[7];
  const float* assign_W = (const float*)d_in[8];
  const float* assign_b = (const float*)d_in[9];
  const int E = in_sizes[0] / 2;
  const int N = in_sizes[1] / 128;
  const int* src = adj;
  const int* dst = adj + E;

  char* ws = (char*)d_ws;
  size_t off = 0;
  auto alloc = [&](size_t bytes) {
    void* p = ws + off;
    off = (off + bytes + 511) & ~(size_t)511;
    return p;
  };
  const int G = 256;
  const int B = (N + 511) >> 9;
  const int L = B * G;
  _Float16* Ph = (_Float16*)alloc((size_t)N * 128 * 2);  // 25.6 MB
  _Float16* Qh = (_Float16*)alloc((size_t)N * 128 * 2);  // 25.6 MB
  _Float16* Wt = (_Float16*)alloc((5 * 16384 + 2048) * 2);
  float* dinv = (float*)alloc((size_t)N * 4);
  int* rowptr = (int*)alloc((size_t)(N + 1) * 4);
  int* col = (int*)alloc((size_t)E * 4);
  uint32_t* tmp = (uint32_t*)alloc((size_t)E * 4);
  int* M = (int*)alloc((size_t)L * 4);
  int* scanned = (int*)alloc((size_t)(L + 1) * 4);
  int* scanscratch = (int*)alloc((size_t)L * 4);
  int* bsum = (int*)alloc(4096);
  int* cnt = (int*)alloc((size_t)N * 4);     // fallback path only
  int* cursor = (int*)alloc((size_t)N * 4);  // fallback path only
  float* S = (float*)Ph;  // assign xw [N,16] fp32 reuses Ph

  wprep_k<<<(5 * 16384 + 2048 + 255) / 256, 256, 0, stream>>>(fc1_W, fc2_W, gcn_W, assign_W, Wt);

  if (N <= (1 << 17)) {
    const int chunk = (E + G - 1) / G;
    const int NBL = (L + SCAN_CHUNK - 1) / SCAN_CHUNK;
    p1a_hist_k<<<G, 256, 0, stream>>>(dst, E, G, B, chunk, M);
    scan_partial_k<<<NBL, 256, 0, stream>>>(M, L, bsum);
    scan_bsum_k<<<1, 64, 0, stream>>>(bsum, NBL);
    scan_apply_k<<<NBL, 256, 0, stream>>>(M, bsum, L, scanned, scanscratch, E);
    p1c_scatter_k<<<G, 256, 0, stream>>>(src, dst, E, G, B, chunk, scanned, tmp);
    p2_build_k<<<B, 256, 0, stream>>>(tmp, scanned, G, N, E, rowptr, col, dinv);
  } else {
    const int NB = (N + SCAN_CHUNK - 1) / SCAN_CHUNK;
    hipMemsetAsync(cnt, 0, (size_t)N * 4, stream);
    count_edges_k<<<2048, 256, 0, stream>>>(dst, E, cnt);
    dinv_k<<<(N + 255) / 256, 256, 0, stream>>>(cnt, dinv, N);
    scan_partial_k<<<NB, 256, 0, stream>>>(cnt, N, bsum);
    scan_bsum_k<<<1, 64, 0, stream>>>(bsum, NB);
    scan_apply_k<<<NB, 256, 0, stream>>>(cnt, bsum, N, rowptr, cursor, E);
    fill_k<<<2048, 256, 0, stream>>>(src, dst, E, cursor, col);
  }

  int gb = (N + 63) / 64;
  int ab = (N + 3) / 4;
  gemm_nolds_k<true, false, true, 8><<<gb, 256, 0, stream>>>(X, Wt, fc1_b, nullptr, Ph, N);
  gemm_nolds_k<true, true, true, 8><<<gb, 256, 0, stream>>>(Ph, Wt + 16384, fc2_b, nullptr, Qh, N);
  for (int l = 0; l < 3; ++l) {
    gemm_nolds_k<false, true, true, 8><<<gb, 256, 0, stream>>>(
        Qh, Wt + (size_t)(2 + l) * 16384, nullptr, dinv, Ph, N);
    agg128h_k<<<ab, 256, 0, stream>>>(Ph, rowptr, col, dinv, gcn_b + (size_t)l * 128, Qh, N);
  }
  gemm_nolds_k<false, true, false, 1><<<gb, 256, 0, stream>>>(Qh, Wt + 5 * 16384, nullptr, dinv,
                                                              S, N);
  agg16_k<<<ab, 256, 0, stream>>>(S, rowptr, col, dinv, assign_b, (float*)d_out, N);
}

// Round 10
// 565.179 us; speedup vs baseline: 1.1189x; 1.1189x over previous
//
#include <hip/hip_runtime.h>
#include <cstdint>
#include <cstddef>

// GraphCluster: 3-layer GCN + assign head, 100K nodes / 1.6M edges.
// R1: hierarchical scan. R2: f16-MFMA GEMMs. R3: f16 intermediates.
// R4 bucketed fill REVERTED (hot-cursor atomics). R6 agg unroll-8 REVERTED.
// R7: scan-based counting-sort CSR build. R8: LDS-free GEMM (neutral — GEMM
// is latency-bound, not conflict-bound: 6 waves/SIMD vs agg's ~100 queued).
// R9: 16-row-tile GEMM (NT=2/wave, 4x grid depth) + lane-ordered W frags
// (B-load = base + lane*16B, single coalesced 1KB/instr).

#define SCAN_CHUNK 2048

typedef _Float16 half8 __attribute__((ext_vector_type(8)));
typedef float floatx4 __attribute__((ext_vector_type(4)));

// ---------------------------------------------------------------- generic scan
__global__ __launch_bounds__(256) void scan_partial_k(const int* __restrict__ cnt, int N,
                                                      int* __restrict__ bsum) {
  __shared__ int red[256];
  int b = blockIdx.x, t = threadIdx.x;
  int base = b * SCAN_CHUNK + t * 8;
  int s = 0;
#pragma unroll
  for (int i = 0; i < 8; ++i) {
    int idx = base + i;
    if (idx < N) s += cnt[idx];
  }
  red[t] = s;
  __syncthreads();
  for (int off = 128; off > 0; off >>= 1) {
    if (t < off) red[t] += red[t + off];
    __syncthreads();
  }
  if (t == 0) bsum[b] = red[0];
}

__global__ __launch_bounds__(64) void scan_bsum_k(int* __restrict__ bsum, int NB) {
  int lane = threadIdx.x;
  int per = (NB + 63) >> 6;
  int beg = lane * per;
  int end = min(beg + per, NB);
  int s = 0;
  for (int i = beg; i < end; ++i) s += bsum[i];
  int ps = s;
  for (int off = 1; off < 64; off <<= 1) {
    int u = __shfl_up(ps, off, 64);
    if (lane >= off) ps += u;
  }
  int run = ps - s;
  for (int i = beg; i < end; ++i) {
    int c = bsum[i];
    bsum[i] = run;
    run += c;
  }
}

__global__ __launch_bounds__(256) void scan_apply_k(const int* __restrict__ cnt,
                                                    const int* __restrict__ bsum_excl, int N,
                                                    int* __restrict__ rowptr,
                                                    int* __restrict__ cursor, int E) {
  __shared__ int wave_sums[4];
  int b = blockIdx.x, t = threadIdx.x;
  int base = b * SCAN_CHUNK + t * 8;
  int v[8];
  int s = 0;
#pragma unroll
  for (int i = 0; i < 8; ++i) {
    int idx = base + i;
    v[i] = (idx < N) ? cnt[idx] : 0;
    s += v[i];
  }
  int lane = t & 63, wave = t >> 6;
  int ps = s;
  for (int off = 1; off < 64; off <<= 1) {
    int u = __shfl_up(ps, off, 64);
    if (lane >= off) ps += u;
  }
  if (lane == 63) wave_sums[wave] = ps;
  __syncthreads();
  int woff = 0;
  for (int w = 0; w < 4; ++w)
    if (w < wave) woff += wave_sums[w];
  int excl = woff + (ps - s) + bsum_excl[b];
#pragma unroll
  for (int i = 0; i < 8; ++i) {
    int idx = base + i;
    if (idx < N) {
      rowptr[idx] = excl;
      cursor[idx] = excl;
      excl += v[i];
    }
  }
  if (b == 0 && t == 0) rowptr[N] = E;
}

// ------------------------------------------------- scan-sorted CSR build
__global__ __launch_bounds__(256) void p1a_hist_k(const int* __restrict__ dst, int E, int G,
                                                  int B, int chunk, int* __restrict__ M) {
  __shared__ int h[256];
  int g = blockIdx.x, t = threadIdx.x;
  for (int i = t; i < B; i += 256) h[i] = 0;
  __syncthreads();
  int ebeg = g * chunk, eend = min(ebeg + chunk, E);
  for (int e = ebeg + t; e < eend; e += 256) atomicAdd(&h[dst[e] >> 9], 1);
  __syncthreads();
  for (int b = t; b < B; b += 256) M[(size_t)b * G + g] = h[b];
}

__global__ __launch_bounds__(256) void p1c_scatter_k(const int* __restrict__ src,
                                                     const int* __restrict__ dst, int E, int G,
                                                     int B, int chunk,
                                                     const int* __restrict__ scanned,
                                                     uint32_t* __restrict__ tmp) {
  __shared__ int off[256];
  int g = blockIdx.x, t = threadIdx.x;
  for (int b = t; b < B; b += 256) off[b] = scanned[(size_t)b * G + g];
  __syncthreads();
  int ebeg = g * chunk, eend = min(ebeg + chunk, E);
  for (int e = ebeg + t; e < eend; e += 256) {
    int d = dst[e];
    int b = d >> 9;
    int pos = atomicAdd(&off[b], 1);  // LDS cursor, private to this block
    tmp[pos] = ((uint32_t)(d & 511) << 17) | (uint32_t)src[e];
  }
}

__global__ __launch_bounds__(256) void p2_build_k(const uint32_t* __restrict__ tmp,
                                                  const int* __restrict__ scanned, int G, int N,
                                                  int E, int* __restrict__ rowptr,
                                                  int* __restrict__ col,
                                                  float* __restrict__ dinv) {
  __shared__ int hist[512];
  __shared__ int cur[512];
  __shared__ int wsum[4];
  int b = blockIdx.x, t = threadIdx.x;
  int node0 = b << 9;
  int nn = min(512, N - node0);
  int sbeg = scanned[(size_t)b * G];
  int send = scanned[(size_t)(b + 1) * G];
  for (int i = t; i < 512; i += 256) hist[i] = 0;
  __syncthreads();
  for (int e = sbeg + t; e < send; e += 256) atomicAdd(&hist[tmp[e] >> 17], 1);
  __syncthreads();
  int h0 = hist[2 * t], h1 = hist[2 * t + 1];
  int s = h0 + h1;
  int lane = t & 63, w = t >> 6;
  int ps = s;
  for (int o = 1; o < 64; o <<= 1) {
    int u = __shfl_up(ps, o, 64);
    if (lane >= o) ps += u;
  }
  if (lane == 63) wsum[w] = ps;
  __syncthreads();
  int woff = 0;
  for (int k = 0; k < 4; ++k)
    if (k < w) woff += wsum[k];
  int excl = sbeg + woff + (ps - s);
  if (2 * t < nn) {
    rowptr[node0 + 2 * t] = excl;
    cur[2 * t] = excl;
    dinv[node0 + 2 * t] = rsqrtf((float)(h0 + 1));
  }
  if (2 * t + 1 < nn) {
    rowptr[node0 + 2 * t + 1] = excl + h0;
    cur[2 * t + 1] = excl + h0;
    dinv[node0 + 2 * t + 1] = rsqrtf((float)(h1 + 1));
  }
  if (b == 0 && t == 0) rowptr[N] = E;
  __syncthreads();
  for (int e = sbeg + t; e < send; e += 256) {
    uint32_t u = tmp[e];
    int pos = atomicAdd(&cur[u >> 17], 1);
    col[pos] = (int)(u & 0x1FFFF);
  }
}

// ------------------------------------------------- fallback CSR build (N large)
__global__ __launch_bounds__(256) void count_edges_k(const int* __restrict__ dst, int E,
                                                     int* __restrict__ cnt) {
  int idx = blockIdx.x * blockDim.x + threadIdx.x;
  int stride = gridDim.x * blockDim.x;
  for (int e = idx; e < E; e += stride) atomicAdd(&cnt[dst[e]], 1);
}

__global__ __launch_bounds__(256) void dinv_k(const int* __restrict__ cnt,
                                              float* __restrict__ dinv, int N) {
  int i = blockIdx.x * blockDim.x + threadIdx.x;
  if (i < N) dinv[i] = rsqrtf((float)(cnt[i] + 1));
}

__global__ __launch_bounds__(256) void fill_k(const int* __restrict__ src,
                                              const int* __restrict__ dst, int E,
                                              int* __restrict__ cursor, int* __restrict__ col) {
  int idx = blockIdx.x * blockDim.x + threadIdx.x;
  int stride = gridDim.x * blockDim.x;
  for (int e = idx; e < E; e += stride) {
    int d = dst[e];
    int pos = atomicAdd(&cursor[d], 1);
    col[pos] = src[e];
  }
}

// ---------------------------------------------------------------- weight prep
// Lane-ordered MFMA B-fragments. 128-col mats (0..4): element
// Wb[mat*16384 + ((t*4+ktb)*64 + lane)*8 + j] = W[(ktb*32+q*8+j)*128 + t*16+m]
// where m=lane&15, q=lane>>4. Assign mat (16 cols) at offset 5*16384:
// Wb[5*16384 + (ktb*64+lane)*8 + j] = assign_W[(ktb*32+q*8+j)*16 + m].
__global__ __launch_bounds__(256) void wprep_k(const float* __restrict__ fc1_W,
                                               const float* __restrict__ fc2_W,
                                               const float* __restrict__ gcn_W,
                                               const float* __restrict__ assign_W,
                                               _Float16* __restrict__ Wb) {
  int idx = blockIdx.x * 256 + threadIdx.x;
  if (idx < 5 * 16384) {
    int mat = idx >> 14;
    int r = idx & 16383;
    int t = r >> 11;
    int ktb = (r >> 9) & 3;
    int lane = (r >> 3) & 63;
    int j = r & 7;
    int m = lane & 15, q = lane >> 4;
    int k = ktb * 32 + q * 8 + j;
    int n = t * 16 + m;
    const float* W = (mat == 0) ? fc1_W : (mat == 1) ? fc2_W : gcn_W + (size_t)(mat - 2) * 16384;
    Wb[idx] = (_Float16)W[(size_t)k * 128 + n];
  } else if (idx < 5 * 16384 + 2048) {
    int r = idx - 5 * 16384;
    int ktb = r >> 9;
    int lane = (r >> 3) & 63;
    int j = r & 7;
    int m = lane & 15, q = lane >> 4;
    int k = ktb * 32 + q * 8 + j;
    Wb[idx] = (_Float16)assign_W[(size_t)k * 16 + m];
  }
}

// ---------------------------------------------------------------- 16-row GEMM
// Block = 256 thr = 4 waves; ALL waves share one 16-row A tile (L1-hit after
// first wave), wave w computes cols [w*32, w*32+32) (NT=2). Grid = N/16 ->
// ~24 waves/SIMD queued (oversubscription hides memory latency; R8/R9's 6
// waves/SIMD was the bottleneck). B-frag loads fully coalesced via Wb layout.
template <bool SIG, bool HIN, bool HOUT>
__global__ __launch_bounds__(256) void gemm128v2_k(const void* __restrict__ Av,
                                                   const _Float16* __restrict__ Wb,
                                                   const float* __restrict__ bias,
                                                   const float* __restrict__ scale,
                                                   void* __restrict__ outv, int N) {
  const int tid = threadIdx.x;
  const int w = tid >> 6, lane = tid & 63;
  const int m = lane & 15, q = lane >> 4;
  const int r0 = blockIdx.x * 16;
  const int rowA = r0 + m;
  const bool validA = rowA < N;
  const int t0 = w * 2;
  floatx4 acc0 = (floatx4){0.f, 0.f, 0.f, 0.f};
  floatx4 acc1 = (floatx4){0.f, 0.f, 0.f, 0.f};
#pragma unroll
  for (int ktb = 0; ktb < 4; ++ktb) {
    half8 a = {0, 0, 0, 0, 0, 0, 0, 0};
    if (validA) {
      if (HIN) {
        a = *(const half8*)((const _Float16*)Av + (size_t)rowA * 128 + ktb * 32 + q * 8);
      } else {
        const float* Ap = (const float*)Av + (size_t)rowA * 128 + ktb * 32 + q * 8;
        float4 f0 = *(const float4*)Ap;
        float4 f1 = *(const float4*)(Ap + 4);
        a[0] = (_Float16)f0.x; a[1] = (_Float16)f0.y;
        a[2] = (_Float16)f0.z; a[3] = (_Float16)f0.w;
        a[4] = (_Float16)f1.x; a[5] = (_Float16)f1.y;
        a[6] = (_Float16)f1.z; a[7] = (_Float16)f1.w;
      }
    }
    half8 b0 = *(const half8*)(Wb + ((size_t)(t0 * 4 + ktb) * 64 + lane) * 8);
    half8 b1 = *(const half8*)(Wb + ((size_t)((t0 + 1) * 4 + ktb) * 64 + lane) * 8);
    acc0 = __builtin_amdgcn_mfma_f32_16x16x32_f16(a, b0, acc0, 0, 0, 0);
    acc1 = __builtin_amdgcn_mfma_f32_16x16x32_f16(a, b1, acc1, 0, 0, 0);
  }
#pragma unroll
  for (int r = 0; r < 4; ++r) {
    int row = r0 + q * 4 + r;
    if (row >= N) continue;
    float sc = scale ? scale[row] : 1.f;
#pragma unroll
    for (int t = 0; t < 2; ++t) {
      int colg = (t0 + t) * 16 + m;
      float v = (t == 0) ? acc0[r] : acc1[r];
      if (bias) v += bias[colg];
      if (SIG) v = 1.f / (1.f + __expf(-v));
      v *= sc;
      if (HOUT)
        ((_Float16*)outv)[(size_t)row * 128 + colg] = (_Float16)v;
      else
        ((float*)outv)[(size_t)row * 128 + colg] = v;
    }
  }
}

// Assign head: out[N,16] fp32 = A[N,128](f16) @ W[128,16], *scale. One 16-row
// tile per wave (4 tiles/block).
__global__ __launch_bounds__(256) void gemm16v2_k(const _Float16* __restrict__ Av,
                                                  const _Float16* __restrict__ Wb16,
                                                  const float* __restrict__ scale,
                                                  float* __restrict__ out, int N) {
  const int tid = threadIdx.x;
  const int w = tid >> 6, lane = tid & 63;
  const int m = lane & 15, q = lane >> 4;
  const int r0 = (blockIdx.x * 4 + w) * 16;
  const int rowA = r0 + m;
  const bool validA = rowA < N;
  floatx4 acc = (floatx4){0.f, 0.f, 0.f, 0.f};
#pragma unroll
  for (int ktb = 0; ktb < 4; ++ktb) {
    half8 a = {0, 0, 0, 0, 0, 0, 0, 0};
    if (validA) a = *(const half8*)(Av + (size_t)rowA * 128 + ktb * 32 + q * 8);
    half8 b = *(const half8*)(Wb16 + ((size_t)ktb * 64 + lane) * 8);
    acc = __builtin_amdgcn_mfma_f32_16x16x32_f16(a, b, acc, 0, 0, 0);
  }
#pragma unroll
  for (int r = 0; r < 4; ++r) {
    int row = r0 + q * 4 + r;
    if (row < N) out[(size_t)row * 16 + m] = acc[r] * scale[row];
  }
}

// ---------------------------------------------------------------- aggregation
// xw (f16, pre-scaled by dinv[row]): out[i] = b + dinv[i]*(xw[i]+sum xw[src]).
__global__ __launch_bounds__(256) void agg128h_k(const _Float16* __restrict__ xw,
                                                 const int* __restrict__ rowptr,
                                                 const int* __restrict__ col,
                                                 const float* __restrict__ dinv,
                                                 const float* __restrict__ bias,
                                                 _Float16* __restrict__ out, int N) {
  int node = blockIdx.x * 4 + (threadIdx.x >> 6);
  if (node >= N) return;
  int lane = threadIdx.x & 63;
  int fl = lane & 15;
  int j = lane >> 4;
  int beg = rowptr[node];
  int end = rowptr[node + 1];
  const _Float16* base = xw + (size_t)fl * 8;
  float a[8] = {0.f, 0.f, 0.f, 0.f, 0.f, 0.f, 0.f, 0.f};
  int e = beg + j;
  for (; e + 12 < end; e += 16) {
    int s0 = col[e], s1 = col[e + 4], s2 = col[e + 8], s3 = col[e + 12];
    half8 v0 = *(const half8*)(base + (size_t)s0 * 128);
    half8 v1 = *(const half8*)(base + (size_t)s1 * 128);
    half8 v2 = *(const half8*)(base + (size_t)s2 * 128);
    half8 v3 = *(const half8*)(base + (size_t)s3 * 128);
#pragma unroll
    for (int f = 0; f < 8; ++f)
      a[f] += ((float)v0[f] + (float)v1[f]) + ((float)v2[f] + (float)v3[f]);
  }
  for (; e < end; e += 4) {
    half8 v = *(const half8*)(base + (size_t)col[e] * 128);
#pragma unroll
    for (int f = 0; f < 8; ++f) a[f] += (float)v[f];
  }
  if (j == 0) {
    half8 v = *(const half8*)(base + (size_t)node * 128);
#pragma unroll
    for (int f = 0; f < 8; ++f) a[f] += (float)v[f];
  }
#pragma unroll
  for (int f = 0; f < 8; ++f) {
    a[f] += __shfl_xor(a[f], 16, 64);
    a[f] += __shfl_xor(a[f], 32, 64);
  }
  if (j == 0) {
    float di = dinv[node];
    float4 b0 = *(const float4*)(bias + fl * 8);
    float4 b1 = *(const float4*)(bias + fl * 8 + 4);
    half8 o;
    o[0] = (_Float16)fmaf(a[0], di, b0.x);
    o[1] = (_Float16)fmaf(a[1], di, b0.y);
    o[2] = (_Float16)fmaf(a[2], di, b0.z);
    o[3] = (_Float16)fmaf(a[3], di, b0.w);
    o[4] = (_Float16)fmaf(a[4], di, b1.x);
    o[5] = (_Float16)fmaf(a[5], di, b1.y);
    o[6] = (_Float16)fmaf(a[6], di, b1.z);
    o[7] = (_Float16)fmaf(a[7], di, b1.w);
    *(half8*)(out + (size_t)node * 128 + fl * 8) = o;
  }
}

__global__ __launch_bounds__(256) void agg16_k(const float* __restrict__ xw,
                                               const int* __restrict__ rowptr,
                                               const int* __restrict__ col,
                                               const float* __restrict__ dinv,
                                               const float* __restrict__ bias,
                                               float* __restrict__ out, int N) {
  int node = blockIdx.x * 4 + (threadIdx.x >> 6);
  if (node >= N) return;
  int lane = threadIdx.x & 63;
  int f = lane & 15;
  int j = lane >> 4;
  int beg = rowptr[node];
  int end = rowptr[node + 1];
  float acc = 0.f;
  for (int e = beg + j; e < end; e += 4) {
    acc += xw[(size_t)col[e] * 16 + f];
  }
  acc += __shfl_xor(acc, 16, 64);
  acc += __shfl_xor(acc, 32, 64);
  float o = fmaf(acc + xw[(size_t)node * 16 + f], dinv[node], bias[f]);
  if (j == 0) out[(size_t)node * 16 + f] = o;
}

// ---------------------------------------------------------------- launch
extern "C" void kernel_launch(void* const* d_in, const int* in_sizes, int n_in,
                              void* d_out, int out_size, void* d_ws, size_t ws_size,
                              hipStream_t stream) {
  const int* adj = (const int*)d_in[0];
  const float* X = (const float*)d_in[1];
  const float* fc1_W = (const float*)d_in[2];
  const float* fc1_b = (const float*)d_in[3];
  const float* fc2_W = (const float*)d_in[4];
  const float* fc2_b = (const float*)d_in[5];
  const float* gcn_W = (const float*)d_in[6];
  const float* gcn_b = (const float*)d_in[7];
  const float* assign_W = (const float*)d_in[8];
  const float* assign_b = (const float*)d_in[9];
  const int E = in_sizes[0] / 2;
  const int N = in_sizes[1] / 128;
  const int* src = adj;
  const int* dst = adj + E;

  char* ws = (char*)d_ws;
  size_t off = 0;
  auto alloc = [&](size_t bytes) {
    void* p = ws + off;
    off = (off + bytes + 511) & ~(size_t)511;
    return p;
  };
  const int G = 256;
  const int B = (N + 511) >> 9;
  const int L = B * G;
  _Float16* Ph = (_Float16*)alloc((size_t)N * 128 * 2);  // 25.6 MB
  _Float16* Qh = (_Float16*)alloc((size_t)N * 128 * 2);  // 25.6 MB
  _Float16* Wb = (_Float16*)alloc((5 * 16384 + 2048) * 2);
  float* dinv = (float*)alloc((size_t)N * 4);
  int* rowptr = (int*)alloc((size_t)(N + 1) * 4);
  int* col = (int*)alloc((size_t)E * 4);
  uint32_t* tmp = (uint32_t*)alloc((size_t)E * 4);
  int* M = (int*)alloc((size_t)L * 4);
  int* scanned = (int*)alloc((size_t)(L + 1) * 4);
  int* scanscratch = (int*)alloc((size_t)L * 4);
  int* bsum = (int*)alloc(4096);
  int* cnt = (int*)alloc((size_t)N * 4);     // fallback path only
  int* cursor = (int*)alloc((size_t)N * 4);  // fallback path only
  float* S = (float*)Ph;  // assign xw [N,16] fp32 reuses Ph

  wprep_k<<<(5 * 16384 + 2048 + 255) / 256, 256, 0, stream>>>(fc1_W, fc2_W, gcn_W, assign_W, Wb);

  if (N <= (1 << 17)) {
    const int chunk = (E + G - 1) / G;
    const int NBL = (L + SCAN_CHUNK - 1) / SCAN_CHUNK;
    p1a_hist_k<<<G, 256, 0, stream>>>(dst, E, G, B, chunk, M);
    scan_partial_k<<<NBL, 256, 0, stream>>>(M, L, bsum);
    scan_bsum_k<<<1, 64, 0, stream>>>(bsum, NBL);
    scan_apply_k<<<NBL, 256, 0, stream>>>(M, bsum, L, scanned, scanscratch, E);
    p1c_scatter_k<<<G, 256, 0, stream>>>(src, dst, E, G, B, chunk, scanned, tmp);
    p2_build_k<<<B, 256, 0, stream>>>(tmp, scanned, G, N, E, rowptr, col, dinv);
  } else {
    const int NB = (N + SCAN_CHUNK - 1) / SCAN_CHUNK;
    hipMemsetAsync(cnt, 0, (size_t)N * 4, stream);
    count_edges_k<<<2048, 256, 0, stream>>>(dst, E, cnt);
    dinv_k<<<(N + 255) / 256, 256, 0, stream>>>(cnt, dinv, N);
    scan_partial_k<<<NB, 256, 0, stream>>>(cnt, N, bsum);
    scan_bsum_k<<<1, 64, 0, stream>>>(bsum, NB);
    scan_apply_k<<<NB, 256, 0, stream>>>(cnt, bsum, N, rowptr, cursor, E);
    fill_k<<<2048, 256, 0, stream>>>(src, dst, E, cursor, col);
  }

  int g16 = (N + 15) / 16;
  int g64 = (N + 63) / 64;
  int ab = (N + 3) / 4;
  gemm128v2_k<true, false, true><<<g16, 256, 0, stream>>>(X, Wb, fc1_b, nullptr, Ph, N);
  gemm128v2_k<true, true, true><<<g16, 256, 0, stream>>>(Ph, Wb + 16384, fc2_b, nullptr, Qh, N);
  for (int l = 0; l < 3; ++l) {
    gemm128v2_k<false, true, true><<<g16, 256, 0, stream>>>(
        Qh, Wb + (size_t)(2 + l) * 16384, nullptr, dinv, Ph, N);
    agg128h_k<<<ab, 256, 0, stream>>>(Ph, rowptr, col, dinv, gcn_b + (size_t)l * 128, Qh, N);
  }
  gemm16v2_k<<<g64, 256, 0, stream>>>(Qh, Wb + 5 * 16384, dinv, S, N);
  agg16_k<<<ab, 256, 0, stream>>>(S, rowptr, col, dinv, assign_b, (float*)d_out, N);
}

// Round 11
// 553.575 us; speedup vs baseline: 1.1423x; 1.0210x over previous
//
#include <hip/hip_runtime.h>
#include <cstdint>
#include <cstddef>

// GraphCluster: 3-layer GCN + assign head, 100K nodes / 1.6M edges.
// R1: hierarchical scan. R2: f16-MFMA GEMMs. R3: f16 intermediates.
// R4 bucketed fill REVERTED (hot-cursor atomics). R6 agg unroll-8 REVERTED.
// R7: scan-based counting-sort CSR build. R8: LDS-free GEMM. R9/R10: 16-row
// GEMM tiles + lane-ordered W frags (GEMMs off the top-5). R11: agg packed-f16
// accumulate (4 v_pk_add_f16 vs 16 cvt+add per edge) + contiguous per-slot
// edge runs (4 gathers in flight for typical deg; old strided tail serialized).

#define SCAN_CHUNK 2048

typedef _Float16 half8 __attribute__((ext_vector_type(8)));
typedef float floatx4 __attribute__((ext_vector_type(4)));

// ---------------------------------------------------------------- generic scan
__global__ __launch_bounds__(256) void scan_partial_k(const int* __restrict__ cnt, int N,
                                                      int* __restrict__ bsum) {
  __shared__ int red[256];
  int b = blockIdx.x, t = threadIdx.x;
  int base = b * SCAN_CHUNK + t * 8;
  int s = 0;
#pragma unroll
  for (int i = 0; i < 8; ++i) {
    int idx = base + i;
    if (idx < N) s += cnt[idx];
  }
  red[t] = s;
  __syncthreads();
  for (int off = 128; off > 0; off >>= 1) {
    if (t < off) red[t] += red[t + off];
    __syncthreads();
  }
  if (t == 0) bsum[b] = red[0];
}

__global__ __launch_bounds__(64) void scan_bsum_k(int* __restrict__ bsum, int NB) {
  int lane = threadIdx.x;
  int per = (NB + 63) >> 6;
  int beg = lane * per;
  int end = min(beg + per, NB);
  int s = 0;
  for (int i = beg; i < end; ++i) s += bsum[i];
  int ps = s;
  for (int off = 1; off < 64; off <<= 1) {
    int u = __shfl_up(ps, off, 64);
    if (lane >= off) ps += u;
  }
  int run = ps - s;
  for (int i = beg; i < end; ++i) {
    int c = bsum[i];
    bsum[i] = run;
    run += c;
  }
}

__global__ __launch_bounds__(256) void scan_apply_k(const int* __restrict__ cnt,
                                                    const int* __restrict__ bsum_excl, int N,
                                                    int* __restrict__ rowptr,
                                                    int* __restrict__ cursor, int E) {
  __shared__ int wave_sums[4];
  int b = blockIdx.x, t = threadIdx.x;
  int base = b * SCAN_CHUNK + t * 8;
  int v[8];
  int s = 0;
#pragma unroll
  for (int i = 0; i < 8; ++i) {
    int idx = base + i;
    v[i] = (idx < N) ? cnt[idx] : 0;
    s += v[i];
  }
  int lane = t & 63, wave = t >> 6;
  int ps = s;
  for (int off = 1; off < 64; off <<= 1) {
    int u = __shfl_up(ps, off, 64);
    if (lane >= off) ps += u;
  }
  if (lane == 63) wave_sums[wave] = ps;
  __syncthreads();
  int woff = 0;
  for (int w = 0; w < 4; ++w)
    if (w < wave) woff += wave_sums[w];
  int excl = woff + (ps - s) + bsum_excl[b];
#pragma unroll
  for (int i = 0; i < 8; ++i) {
    int idx = base + i;
    if (idx < N) {
      rowptr[idx] = excl;
      cursor[idx] = excl;
      excl += v[i];
    }
  }
  if (b == 0 && t == 0) rowptr[N] = E;
}

// ------------------------------------------------- scan-sorted CSR build
__global__ __launch_bounds__(256) void p1a_hist_k(const int* __restrict__ dst, int E, int G,
                                                  int B, int chunk, int* __restrict__ M) {
  __shared__ int h[256];
  int g = blockIdx.x, t = threadIdx.x;
  for (int i = t; i < B; i += 256) h[i] = 0;
  __syncthreads();
  int ebeg = g * chunk, eend = min(ebeg + chunk, E);
  for (int e = ebeg + t; e < eend; e += 256) atomicAdd(&h[dst[e] >> 9], 1);
  __syncthreads();
  for (int b = t; b < B; b += 256) M[(size_t)b * G + g] = h[b];
}

__global__ __launch_bounds__(256) void p1c_scatter_k(const int* __restrict__ src,
                                                     const int* __restrict__ dst, int E, int G,
                                                     int B, int chunk,
                                                     const int* __restrict__ scanned,
                                                     uint32_t* __restrict__ tmp) {
  __shared__ int off[256];
  int g = blockIdx.x, t = threadIdx.x;
  for (int b = t; b < B; b += 256) off[b] = scanned[(size_t)b * G + g];
  __syncthreads();
  int ebeg = g * chunk, eend = min(ebeg + chunk, E);
  for (int e = ebeg + t; e < eend; e += 256) {
    int d = dst[e];
    int b = d >> 9;
    int pos = atomicAdd(&off[b], 1);  // LDS cursor, private to this block
    tmp[pos] = ((uint32_t)(d & 511) << 17) | (uint32_t)src[e];
  }
}

__global__ __launch_bounds__(256) void p2_build_k(const uint32_t* __restrict__ tmp,
                                                  const int* __restrict__ scanned, int G, int N,
                                                  int E, int* __restrict__ rowptr,
                                                  int* __restrict__ col,
                                                  float* __restrict__ dinv) {
  __shared__ int hist[512];
  __shared__ int cur[512];
  __shared__ int wsum[4];
  int b = blockIdx.x, t = threadIdx.x;
  int node0 = b << 9;
  int nn = min(512, N - node0);
  int sbeg = scanned[(size_t)b * G];
  int send = scanned[(size_t)(b + 1) * G];
  for (int i = t; i < 512; i += 256) hist[i] = 0;
  __syncthreads();
  for (int e = sbeg + t; e < send; e += 256) atomicAdd(&hist[tmp[e] >> 17], 1);
  __syncthreads();
  int h0 = hist[2 * t], h1 = hist[2 * t + 1];
  int s = h0 + h1;
  int lane = t & 63, w = t >> 6;
  int ps = s;
  for (int o = 1; o < 64; o <<= 1) {
    int u = __shfl_up(ps, o, 64);
    if (lane >= o) ps += u;
  }
  if (lane == 63) wsum[w] = ps;
  __syncthreads();
  int woff = 0;
  for (int k = 0; k < 4; ++k)
    if (k < w) woff += wsum[k];
  int excl = sbeg + woff + (ps - s);
  if (2 * t < nn) {
    rowptr[node0 + 2 * t] = excl;
    cur[2 * t] = excl;
    dinv[node0 + 2 * t] = rsqrtf((float)(h0 + 1));
  }
  if (2 * t + 1 < nn) {
    rowptr[node0 + 2 * t + 1] = excl + h0;
    cur[2 * t + 1] = excl + h0;
    dinv[node0 + 2 * t + 1] = rsqrtf((float)(h1 + 1));
  }
  if (b == 0 && t == 0) rowptr[N] = E;
  __syncthreads();
  for (int e = sbeg + t; e < send; e += 256) {
    uint32_t u = tmp[e];
    int pos = atomicAdd(&cur[u >> 17], 1);
    col[pos] = (int)(u & 0x1FFFF);
  }
}

// ------------------------------------------------- fallback CSR build (N large)
__global__ __launch_bounds__(256) void count_edges_k(const int* __restrict__ dst, int E,
                                                     int* __restrict__ cnt) {
  int idx = blockIdx.x * blockDim.x + threadIdx.x;
  int stride = gridDim.x * blockDim.x;
  for (int e = idx; e < E; e += stride) atomicAdd(&cnt[dst[e]], 1);
}

__global__ __launch_bounds__(256) void dinv_k(const int* __restrict__ cnt,
                                              float* __restrict__ dinv, int N) {
  int i = blockIdx.x * blockDim.x + threadIdx.x;
  if (i < N) dinv[i] = rsqrtf((float)(cnt[i] + 1));
}

__global__ __launch_bounds__(256) void fill_k(const int* __restrict__ src,
                                              const int* __restrict__ dst, int E,
                                              int* __restrict__ cursor, int* __restrict__ col) {
  int idx = blockIdx.x * blockDim.x + threadIdx.x;
  int stride = gridDim.x * blockDim.x;
  for (int e = idx; e < E; e += stride) {
    int d = dst[e];
    int pos = atomicAdd(&cursor[d], 1);
    col[pos] = src[e];
  }
}

// ---------------------------------------------------------------- weight prep
// Lane-ordered MFMA B-fragments (see R9 comment for layout).
__global__ __launch_bounds__(256) void wprep_k(const float* __restrict__ fc1_W,
                                               const float* __restrict__ fc2_W,
                                               const float* __restrict__ gcn_W,
                                               const float* __restrict__ assign_W,
                                               _Float16* __restrict__ Wb) {
  int idx = blockIdx.x * 256 + threadIdx.x;
  if (idx < 5 * 16384) {
    int mat = idx >> 14;
    int r = idx & 16383;
    int t = r >> 11;
    int ktb = (r >> 9) & 3;
    int lane = (r >> 3) & 63;
    int j = r & 7;
    int m = lane & 15, q = lane >> 4;
    int k = ktb * 32 + q * 8 + j;
    int n = t * 16 + m;
    const float* W = (mat == 0) ? fc1_W : (mat == 1) ? fc2_W : gcn_W + (size_t)(mat - 2) * 16384;
    Wb[idx] = (_Float16)W[(size_t)k * 128 + n];
  } else if (idx < 5 * 16384 + 2048) {
    int r = idx - 5 * 16384;
    int ktb = r >> 9;
    int lane = (r >> 3) & 63;
    int j = r & 7;
    int m = lane & 15, q = lane >> 4;
    int k = ktb * 32 + q * 8 + j;
    Wb[idx] = (_Float16)assign_W[(size_t)k * 16 + m];
  }
}

// ---------------------------------------------------------------- 16-row GEMM
template <bool SIG, bool HIN, bool HOUT>
__global__ __launch_bounds__(256) void gemm128v2_k(const void* __restrict__ Av,
                                                   const _Float16* __restrict__ Wb,
                                                   const float* __restrict__ bias,
                                                   const float* __restrict__ scale,
                                                   void* __restrict__ outv, int N) {
  const int tid = threadIdx.x;
  const int w = tid >> 6, lane = tid & 63;
  const int m = lane & 15, q = lane >> 4;
  const int r0 = blockIdx.x * 16;
  const int rowA = r0 + m;
  const bool validA = rowA < N;
  const int t0 = w * 2;
  floatx4 acc0 = (floatx4){0.f, 0.f, 0.f, 0.f};
  floatx4 acc1 = (floatx4){0.f, 0.f, 0.f, 0.f};
#pragma unroll
  for (int ktb = 0; ktb < 4; ++ktb) {
    half8 a = {0, 0, 0, 0, 0, 0, 0, 0};
    if (validA) {
      if (HIN) {
        a = *(const half8*)((const _Float16*)Av + (size_t)rowA * 128 + ktb * 32 + q * 8);
      } else {
        const float* Ap = (const float*)Av + (size_t)rowA * 128 + ktb * 32 + q * 8;
        float4 f0 = *(const float4*)Ap;
        float4 f1 = *(const float4*)(Ap + 4);
        a[0] = (_Float16)f0.x; a[1] = (_Float16)f0.y;
        a[2] = (_Float16)f0.z; a[3] = (_Float16)f0.w;
        a[4] = (_Float16)f1.x; a[5] = (_Float16)f1.y;
        a[6] = (_Float16)f1.z; a[7] = (_Float16)f1.w;
      }
    }
    half8 b0 = *(const half8*)(Wb + ((size_t)(t0 * 4 + ktb) * 64 + lane) * 8);
    half8 b1 = *(const half8*)(Wb + ((size_t)((t0 + 1) * 4 + ktb) * 64 + lane) * 8);
    acc0 = __builtin_amdgcn_mfma_f32_16x16x32_f16(a, b0, acc0, 0, 0, 0);
    acc1 = __builtin_amdgcn_mfma_f32_16x16x32_f16(a, b1, acc1, 0, 0, 0);
  }
#pragma unroll
  for (int r = 0; r < 4; ++r) {
    int row = r0 + q * 4 + r;
    if (row >= N) continue;
    float sc = scale ? scale[row] : 1.f;
#pragma unroll
    for (int t = 0; t < 2; ++t) {
      int colg = (t0 + t) * 16 + m;
      float v = (t == 0) ? acc0[r] : acc1[r];
      if (bias) v += bias[colg];
      if (SIG) v = 1.f / (1.f + __expf(-v));
      v *= sc;
      if (HOUT)
        ((_Float16*)outv)[(size_t)row * 128 + colg] = (_Float16)v;
      else
        ((float*)outv)[(size_t)row * 128 + colg] = v;
    }
  }
}

__global__ __launch_bounds__(256) void gemm16v2_k(const _Float16* __restrict__ Av,
                                                  const _Float16* __restrict__ Wb16,
                                                  const float* __restrict__ scale,
                                                  float* __restrict__ out, int N) {
  const int tid = threadIdx.x;
  const int w = tid >> 6, lane = tid & 63;
  const int m = lane & 15, q = lane >> 4;
  const int r0 = (blockIdx.x * 4 + w) * 16;
  const int rowA = r0 + m;
  const bool validA = rowA < N;
  floatx4 acc = (floatx4){0.f, 0.f, 0.f, 0.f};
#pragma unroll
  for (int ktb = 0; ktb < 4; ++ktb) {
    half8 a = {0, 0, 0, 0, 0, 0, 0, 0};
    if (validA) a = *(const half8*)(Av + (size_t)rowA * 128 + ktb * 32 + q * 8);
    half8 b = *(const half8*)(Wb16 + ((size_t)ktb * 64 + lane) * 8);
    acc = __builtin_amdgcn_mfma_f32_16x16x32_f16(a, b, acc, 0, 0, 0);
  }
#pragma unroll
  for (int r = 0; r < 4; ++r) {
    int row = r0 + q * 4 + r;
    if (row < N) out[(size_t)row * 16 + m] = acc[r] * scale[row];
  }
}

// ---------------------------------------------------------------- aggregation
// xw (f16, pre-scaled by dinv[row]): out[i] = b + dinv[i]*(xw[i]+sum xw[src]).
// One wave/node; 16 lanes x half8 cover the row. Slot j (lane>>4) handles a
// CONTIGUOUS quarter of the edge list, gathered 4-wide with packed-f16 adds.
__global__ __launch_bounds__(256) void agg128h_k(const _Float16* __restrict__ xw,
                                                 const int* __restrict__ rowptr,
                                                 const int* __restrict__ col,
                                                 const float* __restrict__ dinv,
                                                 const float* __restrict__ bias,
                                                 _Float16* __restrict__ out, int N) {
  int node = blockIdx.x * 4 + (threadIdx.x >> 6);
  if (node >= N) return;
  int lane = threadIdx.x & 63;
  int fl = lane & 15;
  int j = lane >> 4;
  int beg = rowptr[node];
  int end = rowptr[node + 1];
  int deg = end - beg;
  const _Float16* base = xw + (size_t)fl * 8;
  half8 ah = {0, 0, 0, 0, 0, 0, 0, 0};
  int q = (deg + 3) >> 2;
  int e = beg + j * q;
  int e1 = min(e + q, end);
  for (; e + 3 < e1; e += 4) {
    int s0 = col[e], s1 = col[e + 1], s2 = col[e + 2], s3 = col[e + 3];
    half8 v0 = *(const half8*)(base + (size_t)s0 * 128);
    half8 v1 = *(const half8*)(base + (size_t)s1 * 128);
    half8 v2 = *(const half8*)(base + (size_t)s2 * 128);
    half8 v3 = *(const half8*)(base + (size_t)s3 * 128);
    ah += (v0 + v1) + (v2 + v3);
  }
  if (e + 1 < e1) {
    int s0 = col[e], s1 = col[e + 1];
    half8 v0 = *(const half8*)(base + (size_t)s0 * 128);
    half8 v1 = *(const half8*)(base + (size_t)s1 * 128);
    ah += v0 + v1;
    e += 2;
  }
  if (e < e1) {
    ah += *(const half8*)(base + (size_t)col[e] * 128);
  }
  if (j == 0) {  // self-loop term once
    ah += *(const half8*)(base + (size_t)node * 128);
  }
  float a[8];
#pragma unroll
  for (int f = 0; f < 8; ++f) a[f] = (float)ah[f];
#pragma unroll
  for (int f = 0; f < 8; ++f) {
    a[f] += __shfl_xor(a[f], 16, 64);
    a[f] += __shfl_xor(a[f], 32, 64);
  }
  if (j == 0) {
    float di = dinv[node];
    float4 b0 = *(const float4*)(bias + fl * 8);
    float4 b1 = *(const float4*)(bias + fl * 8 + 4);
    half8 o;
    o[0] = (_Float16)fmaf(a[0], di, b0.x);
    o[1] = (_Float16)fmaf(a[1], di, b0.y);
    o[2] = (_Float16)fmaf(a[2], di, b0.z);
    o[3] = (_Float16)fmaf(a[3], di, b0.w);
    o[4] = (_Float16)fmaf(a[4], di, b1.x);
    o[5] = (_Float16)fmaf(a[5], di, b1.y);
    o[6] = (_Float16)fmaf(a[6], di, b1.z);
    o[7] = (_Float16)fmaf(a[7], di, b1.w);
    *(half8*)(out + (size_t)node * 128 + fl * 8) = o;
  }
}

__global__ __launch_bounds__(256) void agg16_k(const float* __restrict__ xw,
                                               const int* __restrict__ rowptr,
                                               const int* __restrict__ col,
                                               const float* __restrict__ dinv,
                                               const float* __restrict__ bias,
                                               float* __restrict__ out, int N) {
  int node = blockIdx.x * 4 + (threadIdx.x >> 6);
  if (node >= N) return;
  int lane = threadIdx.x & 63;
  int f = lane & 15;
  int j = lane >> 4;
  int beg = rowptr[node];
  int end = rowptr[node + 1];
  int deg = end - beg;
  int q = (deg + 3) >> 2;
  int e = beg + j * q;
  int e1 = min(e + q, end);
  float acc = 0.f;
  for (; e + 3 < e1; e += 4) {
    float v0 = xw[(size_t)col[e] * 16 + f];
    float v1 = xw[(size_t)col[e + 1] * 16 + f];
    float v2 = xw[(size_t)col[e + 2] * 16 + f];
    float v3 = xw[(size_t)col[e + 3] * 16 + f];
    acc += (v0 + v1) + (v2 + v3);
  }
  for (; e < e1; ++e) acc += xw[(size_t)col[e] * 16 + f];
  acc += __shfl_xor(acc, 16, 64);
  acc += __shfl_xor(acc, 32, 64);
  float o = fmaf(acc + xw[(size_t)node * 16 + f], dinv[node], bias[f]);
  if (j == 0) out[(size_t)node * 16 + f] = o;
}

// ---------------------------------------------------------------- launch
extern "C" void kernel_launch(void* const* d_in, const int* in_sizes, int n_in,
                              void* d_out, int out_size, void* d_ws, size_t ws_size,
                              hipStream_t stream) {
  const int* adj = (const int*)d_in[0];
  const float* X = (const float*)d_in[1];
  const float* fc1_W = (const float*)d_in[2];
  const float* fc1_b = (const float*)d_in[3];
  const float* fc2_W = (const float*)d_in[4];
  const float* fc2_b = (const float*)d_in[5];
  const float* gcn_W = (const float*)d_in[6];
  const float* gcn_b = (const float*)d_in[7];
  const float* assign_W = (const float*)d_in[8];
  const float* assign_b = (const float*)d_in[9];
  const int E = in_sizes[0] / 2;
  const int N = in_sizes[1] / 128;
  const int* src = adj;
  const int* dst = adj + E;

  char* ws = (char*)d_ws;
  size_t off = 0;
  auto alloc = [&](size_t bytes) {
    void* p = ws + off;
    off = (off + bytes + 511) & ~(size_t)511;
    return p;
  };
  const int G = 256;
  const int B = (N + 511) >> 9;
  const int L = B * G;
  _Float16* Ph = (_Float16*)alloc((size_t)N * 128 * 2);  // 25.6 MB
  _Float16* Qh = (_Float16*)alloc((size_t)N * 128 * 2);  // 25.6 MB
  _Float16* Wb = (_Float16*)alloc((5 * 16384 + 2048) * 2);
  float* dinv = (float*)alloc((size_t)N * 4);
  int* rowptr = (int*)alloc((size_t)(N + 1) * 4);
  int* col = (int*)alloc((size_t)E * 4);
  uint32_t* tmp = (uint32_t*)alloc((size_t)E * 4);
  int* M = (int*)alloc((size_t)L * 4);
  int* scanned = (int*)alloc((size_t)(L + 1) * 4);
  int* scanscratch = (int*)alloc((size_t)L * 4);
  int* bsum = (int*)alloc(4096);
  int* cnt = (int*)alloc((size_t)N * 4);     // fallback path only
  int* cursor = (int*)alloc((size_t)N * 4);  // fallback path only
  float* S = (float*)Ph;  // assign xw [N,16] fp32 reuses Ph

  wprep_k<<<(5 * 16384 + 2048 + 255) / 256, 256, 0, stream>>>(fc1_W, fc2_W, gcn_W, assign_W, Wb);

  if (N <= (1 << 17)) {
    const int chunk = (E + G - 1) / G;
    const int NBL = (L + SCAN_CHUNK - 1) / SCAN_CHUNK;
    p1a_hist_k<<<G, 256, 0, stream>>>(dst, E, G, B, chunk, M);
    scan_partial_k<<<NBL, 256, 0, stream>>>(M, L, bsum);
    scan_bsum_k<<<1, 64, 0, stream>>>(bsum, NBL);
    scan_apply_k<<<NBL, 256, 0, stream>>>(M, bsum, L, scanned, scanscratch, E);
    p1c_scatter_k<<<G, 256, 0, stream>>>(src, dst, E, G, B, chunk, scanned, tmp);
    p2_build_k<<<B, 256, 0, stream>>>(tmp, scanned, G, N, E, rowptr, col, dinv);
  } else {
    const int NB = (N + SCAN_CHUNK - 1) / SCAN_CHUNK;
    hipMemsetAsync(cnt, 0, (size_t)N * 4, stream);
    count_edges_k<<<2048, 256, 0, stream>>>(dst, E, cnt);
    dinv_k<<<(N + 255) / 256, 256, 0, stream>>>(cnt, dinv, N);
    scan_partial_k<<<NB, 256, 0, stream>>>(cnt, N, bsum);
    scan_bsum_k<<<1, 64, 0, stream>>>(bsum, NB);
    scan_apply_k<<<NB, 256, 0, stream>>>(cnt, bsum, N, rowptr, cursor, E);
    fill_k<<<2048, 256, 0, stream>>>(src, dst, E, cursor, col);
  }

  int g16 = (N + 15) / 16;
  int g64 = (N + 63) / 64;
  int ab = (N + 3) / 4;
  gemm128v2_k<true, false, true><<<g16, 256, 0, stream>>>(X, Wb, fc1_b, nullptr, Ph, N);
  gemm128v2_k<true, true, true><<<g16, 256, 0, stream>>>(Ph, Wb + 16384, fc2_b, nullptr, Qh, N);
  for (int l = 0; l < 3; ++l) {
    gemm128v2_k<false, true, true><<<g16, 256, 0, stream>>>(
        Qh, Wb + (size_t)(2 + l) * 16384, nullptr, dinv, Ph, N);
    agg128h_k<<<ab, 256, 0, stream>>>(Ph, rowptr, col, dinv, gcn_b + (size_t)l * 128, Qh, N);
  }
  gemm16v2_k<<<g64, 256, 0, stream>>>(Qh, Wb + 5 * 16384, dinv, S, N);
  agg16_k<<<ab, 256, 0, stream>>>(S, rowptr, col, dinv, assign_b, (float*)d_out, N);
}